// Round 3
// baseline (293.527 us; speedup 1.0000x reference)
//
#include <hip/hip_runtime.h>
#include <hip/hip_bf16.h>

#define B_   32
#define NS_  16
#define NP_  8
#define C_   256
#define T_   128
#define M_   (T_*T_)      // 16384
#define NF_  144          // 128 phrase rows + 16 sentence rows
#define MT_  64           // m-columns per block (4 waves x 16)
#define KC_  32           // k per chunk
#define NCH_ (C_/KC_)     // 8 chunks
#define ABUF_DW 2304      // dwords per A chunk (144 rows x 32 shorts)

typedef __attribute__((ext_vector_type(4))) float f32x4;
typedef __attribute__((ext_vector_type(8))) short s16x8;
typedef __attribute__((ext_vector_type(4))) int   i32x4;

__device__ __forceinline__ short f2bf(float f) {
  unsigned u = __builtin_bit_cast(unsigned, f);
  u += 0x7fffu + ((u >> 16) & 1u);
  return (short)(u >> 16);
}
__device__ __forceinline__ int cvt_pk_bf16(float a, float b) {
  int d;
  asm("v_cvt_pk_bf16_f32 %0, %1, %2" : "=v"(d) : "v"(a), "v"(b));
  return d;  // lo16 = bf16(a), hi16 = bf16(b)
}
__device__ __forceinline__ float sigm(float z) { return 1.0f / (1.0f + __expf(-z)); }

// ---------------- kernel 1: normalize features -> bf16, chunk-major layout ----------------
// Fb layout: [b][kc][row][32 shorts], within 32: pos = 8*g + 4*half + j for
// k = 32*kc + half*16 + 4*g + j  (std MFMA slot order per 16B fragment)
__global__ void prep_feats(const float* __restrict__ sf, const float* __restrict__ pf,
                           short* __restrict__ Fb) {
  const int bs = blockIdx.x;          // b*16 + s
  const int b  = bs >> 4, s = bs & 15;
  const int t  = threadIdx.x;         // c index 0..255
  __shared__ float red[4];
  const int kc   = t >> 5;
  const int kk   = t & 31;
  const int half = kk >> 4;
  const int g    = (kk & 15) >> 2;
  const int j    = kk & 3;
  const int pos  = 8 * g + 4 * half + j;
  for (int v = 0; v < 9; ++v) {
    float x = (v < 8) ? pf[(((size_t)bs) * NP_ + v) * C_ + t]
                      : sf[((size_t)bs) * C_ + t];
    float ss = x * x;
    #pragma unroll
    for (int off = 32; off; off >>= 1) ss += __shfl_xor(ss, off);
    __syncthreads();
    if ((t & 63) == 0) red[t >> 6] = ss;
    __syncthreads();
    const float tot = red[0] + red[1] + red[2] + red[3];
    const float rn = 1.0f / fmaxf(sqrtf(tot), 1e-12f);
    const int row = (v < 8) ? (s * NP_ + v) : (128 + s);
    Fb[(((size_t)(b * 8 + kc)) * NF_ + row) * 32 + pos] = f2bf(x * rn);
  }
}

// ---------------- kernel 2: barrier-free direct-load GEMM + epilogue ----------------
// 256 threads = 4 waves; wave w owns cols [m0+16w, m0+16w+16).
// No LDS staging: B-fragments loaded per-lane from V (64B-coalesced per g-group),
// A-fragments loaded from Fb (L1/L2-resident, 73KB per batch). No k-loop barriers.
__global__ void __launch_bounds__(256, 4) trm_main(
    const float* __restrict__ V,   // (B,C,T,T)
    const int* __restrict__ FbD,   // (B,8,144,32) bf16 as dwords
    const float* __restrict__ pw,
    const float* __restrict__ pm,
    float* __restrict__ out0,      // (B,NS,T,T)
    float* __restrict__ out1) {    // (B,NS,NP,T,T)
  __shared__ float pwl[128];
  __shared__ float pml[128];
  __shared__ float att[16 * 68];   // [s][col] exchange, padded stride

  const int tid  = threadIdx.x;
  const int b    = blockIdx.y;
  const int tile = blockIdx.x;
  const int m0   = tile * MT_;

  const int lane = tid & 63;
  const int w    = tid >> 6;       // 0..3
  const int g    = lane >> 4;      // 0..3
  const int cc   = lane & 15;
  const int col  = w * 16 + cc;    // 0..63
  const int m    = m0 + col;

  if (tid < 128) { pwl[tid] = pw[b * 128 + tid]; pml[tid] = pm[b * 128 + tid]; }

  const float* Vb = V + (size_t)b * C_ * M_ + m;           // per-lane column base
  const int*   Ab = FbD + (size_t)b * 8 * ABUF_DW + cc * 16 + g * 4;

  f32x4 acc[9];
  #pragma unroll
  for (int i = 0; i < 9; ++i) acc[i] = (f32x4){0.f, 0.f, 0.f, 0.f};

  float ssq = 0.f;
  float c0[8], c1[8];
  const int kb0 = 4 * g;

  // prologue: load chunk 0
  #pragma unroll
  for (int j = 0; j < 4; ++j) {
    c0[j]     = Vb[(size_t)(kb0 + j) * M_];
    c0[j + 4] = Vb[(size_t)(16 + kb0 + j) * M_];
  }

  #pragma unroll
  for (int kc = 0; kc < NCH_; ++kc) {
    // prefetch next chunk's V fragments
    if (kc < NCH_ - 1) {
      const int kb = (kc + 1) * KC_ + kb0;
      #pragma unroll
      for (int j = 0; j < 4; ++j) {
        c1[j]     = Vb[(size_t)(kb + j) * M_];
        c1[j + 4] = Vb[(size_t)(16 + kb + j) * M_];
      }
    }
    // pack current chunk -> bf16 fragment, accumulate column ssq
    #pragma unroll
    for (int j = 0; j < 8; ++j) ssq += c0[j] * c0[j];
    i32x4 pk;
    pk[0] = cvt_pk_bf16(c0[0], c0[1]);
    pk[1] = cvt_pk_bf16(c0[2], c0[3]);
    pk[2] = cvt_pk_bf16(c0[4], c0[5]);
    pk[3] = cvt_pk_bf16(c0[6], c0[7]);
    const s16x8 bf = __builtin_bit_cast(s16x8, pk);
    // A fragments (cached) + MFMA
    const int* Ak = Ab + kc * ABUF_DW;
    #pragma unroll
    for (int ft = 0; ft < 9; ++ft) {
      const i32x4 aw = *(const i32x4*)(Ak + ft * 256);
      const s16x8 af = __builtin_bit_cast(s16x8, aw);
      acc[ft] = __builtin_amdgcn_mfma_f32_16x16x32_bf16(af, bf, acc[ft], 0, 0, 0);
    }
    // rotate prefetch regs (renamed away by unroll)
    #pragma unroll
    for (int j = 0; j < 8; ++j) c0[j] = c1[j];
  }

  // ---- column norm: per-lane partial + reduce over the 4 g-lanes of this column
  ssq += __shfl_xor(ssq, 16);
  ssq += __shfl_xor(ssq, 32);
  const float rn = 1.0f / fmaxf(sqrtf(ssq), 1e-12f);

  __syncthreads();   // pwl/pml visible

  const int   t1  = m >> 7;
  const float msk = ((m & 127) >= t1) ? 1.0f : 0.0f;
  const size_t o1base = ((size_t)b * (NS_ * NP_)) << 14;

  // ---- phrase outputs + ph_att
  #pragma unroll
  for (int ft = 0; ft < 8; ++ft) {
    float pa = 0.f;
    #pragma unroll
    for (int rr = 0; rr < 4; ++rr) {
      const int f = ft * 16 + 4 * g + rr;
      const float raw = acc[ft][rr] * rn;
      __builtin_nontemporal_store(sigm(10.0f * raw) * msk * pml[f],
                                  &out1[o1base + ((size_t)f << 14) + m]);
      pa += pwl[f] * raw;
    }
    pa += __shfl_xor(pa, 16);
    if ((g & 1) == 0) att[(2 * ft + (g >> 1)) * 68 + col] = pa;
  }
  __syncthreads();
  // ---- sentence output
  #pragma unroll
  for (int rr = 0; rr < 4; ++rr) {
    const int s = 4 * g + rr;
    const float sfv = acc[8][rr] * rn;
    const float pa = att[s * 68 + col];
    __builtin_nontemporal_store(sigm(10.0f * (sfv + 0.5f * pa)) * msk,
                                &out0[(((size_t)(b * NS_ + s)) << 14) + m]);
  }
}

extern "C" void kernel_launch(void* const* d_in, const int* in_sizes, int n_in,
                              void* d_out, int out_size, void* d_ws, size_t ws_size,
                              hipStream_t stream) {
  const float* V  = (const float*)d_in[0];
  const float* sf = (const float*)d_in[1];
  const float* pf = (const float*)d_in[2];
  const float* pw = (const float*)d_in[3];
  const float* pm = (const float*)d_in[4];
  float* out0 = (float*)d_out;
  float* out1 = out0 + (size_t)B_ * NS_ * M_;
  short* Fb = (short*)d_ws;   // (B,8,144,32) bf16, fragment-ordered

  prep_feats<<<B_ * NS_, 256, 0, stream>>>(sf, pf, Fb);
  dim3 grid(M_ / MT_, B_);
  trm_main<<<grid, 256, 0, stream>>>(V, (const int*)Fb, pw, pm, out0, out1);
}